// Round 1
// baseline (392.270 us; speedup 1.0000x reference)
//
#include <hip/hip_runtime.h>

#define LL 512
#define BB 32
#define DD 256
#define NS 16
#define RK 16
// x_dbl cols = RK + 2*NS = 48

// ---------------- K1: projections ----------------
// delta = softplus(flow @ x_proj_w[:16].T @ dt_proj_w.T + dt_b)   (B,L,D)
// Bm = flow @ x_proj_w[16:32].T   (B,L,16)
// Cm = flow @ x_proj_w[32:48].T   (B,L,16)
__global__ __launch_bounds__(256) void k1_proj(
    const float* __restrict__ flow,       // (L,B,D)
    const float* __restrict__ x_proj_w,   // (48,D)
    const float* __restrict__ dt_w,       // (D,RK)
    const float* __restrict__ dt_b,       // (D)
    float* __restrict__ delta,            // (B,L,D)
    float* __restrict__ Bm,               // (B,L,NS)
    float* __restrict__ Cm)               // (B,L,NS)
{
    const int ROWS = 16;
    const int WP = 260;                   // padded row stride (16B-aligned, decent banks)
    __shared__ float sW[24 * WP];         // half of x_proj_w at a time: 24.96 KB
    __shared__ float sflow[ROWS * DD];    // 16 KB
    __shared__ float sdbl[ROWS * 48];     // 3 KB
    int tid = threadIdx.x;
    int row0 = blockIdx.x * ROWS;         // row = b*L + l

    // stage flow rows (16 rows x 256 floats, float4 loads)
    for (int j = 0; j < 4; ++j) {
        int s = tid + j * 256;            // float4 slot 0..1023
        int r = s >> 6, c4 = s & 63;
        int row = row0 + r;
        int b = row >> 9, l = row & 511;
        float4 v = *reinterpret_cast<const float4*>(&flow[(l * BB + b) * DD + c4 * 4]);
        *reinterpret_cast<float4*>(&sflow[r * DD + c4 * 4]) = v;
    }

    // x_dbl in two halves of 24 output-cols each (keeps LDS < 64KB)
    for (int half = 0; half < 2; ++half) {
        __syncthreads();                  // covers sflow (half 0) and sW reuse (half 1)
        for (int idx = tid; idx < 24 * DD; idx += 256) {
            int c = idx >> 8, k = idx & 255;
            sW[c * WP + k] = x_proj_w[(half * 24 + c) * DD + k];
        }
        __syncthreads();
        for (int o = tid; o < ROWS * 24; o += 256) {
            int r = o / 24, c = o % 24;
            const float* wrow = &sW[c * WP];
            const float* frow = &sflow[r * DD];
            float s = 0.f;
            for (int k = 0; k < DD; k += 4) {
                float4 fv = *reinterpret_cast<const float4*>(&frow[k]);
                float4 wv = *reinterpret_cast<const float4*>(&wrow[k]);
                s += fv.x * wv.x + fv.y * wv.y + fv.z * wv.z + fv.w * wv.w;
            }
            sdbl[r * 48 + half * 24 + c] = s;
        }
    }
    __syncthreads();

    // Bm / Cm: 16 rows x 16 cols each, one element per thread
    {
        int r = tid >> 4, c = tid & 15;
        int row = row0 + r;
        Bm[row * NS + c] = sdbl[r * 48 + RK + c];
        Cm[row * NS + c] = sdbl[r * 48 + RK + NS + c];
    }

    // delta: thread owns channel d = tid, loops over 16 rows
    float wreg[RK];
    #pragma unroll
    for (int k = 0; k < RK; k += 4) {
        float4 v = *reinterpret_cast<const float4*>(&dt_w[tid * RK + k]);
        wreg[k] = v.x; wreg[k + 1] = v.y; wreg[k + 2] = v.z; wreg[k + 3] = v.w;
    }
    float bias = dt_b[tid];
    for (int r = 0; r < ROWS; ++r) {
        float s = bias;
        #pragma unroll
        for (int k = 0; k < RK; ++k) s = fmaf(sdbl[r * 48 + k], wreg[k], s);
        // stable softplus: max(s,0) + log1p(exp(-|s|))
        float sp = fmaxf(s, 0.f) + log1pf(__expf(-fabsf(s)));
        delta[(row0 + r) * DD + tid] = sp;
    }
}

// ---------------- K2: selective scan ----------------
// thread t -> (b, d, n);  h = exp(delta*A)*h + delta*B*u;  y = sum_n h*C + u*D
__global__ __launch_bounds__(256) void k2_scan(
    const float* __restrict__ u_pos,    // (L,B,D)  position_features
    const float* __restrict__ h0,       // (B,D,NS)
    const float* __restrict__ A_log,    // (D,NS)
    const float* __restrict__ Dp,       // (D)
    const float* __restrict__ delta,    // (B,L,D)
    const float* __restrict__ Bm,       // (B,L,NS)
    const float* __restrict__ Cm,       // (B,L,NS)
    float* __restrict__ y,              // (B,L,D)
    float* __restrict__ h_out)          // (B,D,NS) -> tail of d_out
{
    int t = blockIdx.x * 256 + threadIdx.x;
    int n = t & 15;
    int d = (t >> 4) & 255;
    int b = t >> 12;

    float a  = -__expf(A_log[d * NS + n]);
    float Dd = Dp[d];
    float h  = h0[t];                   // (b*256+d)*16+n == t

    const float* dp = delta + (size_t)b * LL * DD + d;
    const float* up = u_pos + b * DD + d;
    const float* Bp = Bm + (size_t)b * LL * NS + n;
    const float* Cp = Cm + (size_t)b * LL * NS + n;
    float* yp = y + (size_t)b * LL * DD + d;

    #pragma unroll 4
    for (int l = 0; l < LL; ++l) {
        float dlt = dp[l * DD];
        float uv  = up[l * BB * DD];
        float Bv  = Bp[l * NS];
        float Cv  = Cp[l * NS];
        float dA  = __expf(dlt * a);
        h = fmaf(dA, h, dlt * Bv * uv);
        float p = h * Cv;
        p += __shfl_xor(p, 1);
        p += __shfl_xor(p, 2);
        p += __shfl_xor(p, 4);
        p += __shfl_xor(p, 8);
        if (n == 0) yp[l * DD] = fmaf(uv, Dd, p);
    }
    h_out[t] = h;
}

// ---------------- K3: output projection ----------------
// Out (16384,256) = Y (16384,256) @ W(256,256)^T   (fp32 vector, 64x64 tile)
__global__ __launch_bounds__(256) void k3_out(
    const float* __restrict__ Y,
    const float* __restrict__ W,        // (m,k) row-major
    float* __restrict__ Out)
{
    __shared__ float As[64 * 68];       // As[k][r]
    __shared__ float Bs[64 * 68];       // Bs[k][m]
    int tid = threadIdx.x;
    int row0 = (blockIdx.x >> 2) * 64;
    int col0 = (blockIdx.x & 3) * 64;
    int tx = tid & 15, ty = tid >> 4;
    int r0 = ty * 4, m0 = tx * 4;
    float acc[4][4] = {};

    for (int kc = 0; kc < 256; kc += 64) {
        __syncthreads();
        for (int j = 0; j < 4; ++j) {
            int s = tid + j * 256;      // 1024 float4 slots
            int r = s >> 4, c4 = s & 15;
            float4 v = *reinterpret_cast<const float4*>(&Y[(row0 + r) * 256 + kc + c4 * 4]);
            As[(c4 * 4 + 0) * 68 + r] = v.x;
            As[(c4 * 4 + 1) * 68 + r] = v.y;
            As[(c4 * 4 + 2) * 68 + r] = v.z;
            As[(c4 * 4 + 3) * 68 + r] = v.w;
        }
        for (int j = 0; j < 4; ++j) {
            int s = tid + j * 256;
            int m = s >> 4, c4 = s & 15;
            float4 v = *reinterpret_cast<const float4*>(&W[(col0 + m) * 256 + kc + c4 * 4]);
            Bs[(c4 * 4 + 0) * 68 + m] = v.x;
            Bs[(c4 * 4 + 1) * 68 + m] = v.y;
            Bs[(c4 * 4 + 2) * 68 + m] = v.z;
            Bs[(c4 * 4 + 3) * 68 + m] = v.w;
        }
        __syncthreads();
        #pragma unroll
        for (int kk = 0; kk < 64; ++kk) {
            float4 av = *reinterpret_cast<const float4*>(&As[kk * 68 + r0]);
            float4 bv = *reinterpret_cast<const float4*>(&Bs[kk * 68 + m0]);
            float aa[4] = {av.x, av.y, av.z, av.w};
            float bb[4] = {bv.x, bv.y, bv.z, bv.w};
            #pragma unroll
            for (int i = 0; i < 4; ++i)
                #pragma unroll
                for (int jj = 0; jj < 4; ++jj)
                    acc[i][jj] = fmaf(aa[i], bb[jj], acc[i][jj]);
        }
    }
    for (int i = 0; i < 4; ++i) {
        float4 v = make_float4(acc[i][0], acc[i][1], acc[i][2], acc[i][3]);
        *reinterpret_cast<float4*>(&Out[(row0 + r0 + i) * 256 + col0 + m0]) = v;
    }
}

extern "C" void kernel_launch(void* const* d_in, const int* in_sizes, int n_in,
                              void* d_out, int out_size, void* d_ws, size_t ws_size,
                              hipStream_t stream) {
    const float* pos  = (const float*)d_in[0];   // (L,B,D)
    const float* flow = (const float*)d_in[1];   // (L,B,D)
    const float* h0   = (const float*)d_in[2];   // (B,D,NS)
    const float* xw   = (const float*)d_in[3];   // (48,D)
    const float* dtw  = (const float*)d_in[4];   // (D,16)
    const float* dtb  = (const float*)d_in[5];   // (D)
    const float* alog = (const float*)d_in[6];   // (D,NS)
    const float* dpar = (const float*)d_in[7];   // (D)
    const float* ow   = (const float*)d_in[8];   // (D_MODEL, D_INNER)

    float* out = (float*)d_out;                  // out0: 4,194,304 then h_final: 131,072

    float* ws    = (float*)d_ws;
    float* delta = ws;                 // 4,194,304 floats
    float* Bmw   = ws + 4194304;       //   262,144
    float* Cmw   = ws + 4456448;       //   262,144
    float* yw    = ws + 4718592;       // 4,194,304   (total ~36.5 MB)

    float* h_out = out + 32 * 512 * 256;

    k1_proj<<<1024, 256, 0, stream>>>(flow, xw, dtw, dtb, delta, Bmw, Cmw);
    k2_scan<<<512, 256, 0, stream>>>(pos, h0, alog, dpar, delta, Bmw, Cmw, yw, h_out);
    k3_out<<<1024, 256, 0, stream>>>(yw, ow, out);
}

// Round 2
// 239.561 us; speedup vs baseline: 1.6375x; 1.6375x over previous
//
#include <hip/hip_runtime.h>

#define LL 512
#define BB 32
#define DD 256
#define NS 16
#define RK 16
#define CH 16          // chunks over L
#define LC 32          // L per chunk

// load 16 consecutive floats into a scalar array (float4 x4)
#define LD16(dst, src, off) { \
  float4 _v0 = *reinterpret_cast<const float4*>(&(src)[(off)]); \
  float4 _v1 = *reinterpret_cast<const float4*>(&(src)[(off)+4]); \
  float4 _v2 = *reinterpret_cast<const float4*>(&(src)[(off)+8]); \
  float4 _v3 = *reinterpret_cast<const float4*>(&(src)[(off)+12]); \
  dst[0]=_v0.x; dst[1]=_v0.y; dst[2]=_v0.z; dst[3]=_v0.w; \
  dst[4]=_v1.x; dst[5]=_v1.y; dst[6]=_v1.z; dst[7]=_v1.w; \
  dst[8]=_v2.x; dst[9]=_v2.y; dst[10]=_v2.z; dst[11]=_v2.w; \
  dst[12]=_v3.x; dst[13]=_v3.y; dst[14]=_v3.z; dst[15]=_v3.w; }

// ---------------- K1: projections ----------------
__global__ __launch_bounds__(256) void k1_proj(
    const float* __restrict__ flow,       // (L,B,D)
    const float* __restrict__ x_proj_w,   // (48,D)
    const float* __restrict__ dt_w,       // (D,RK)
    const float* __restrict__ dt_b,       // (D)
    float* __restrict__ delta,            // (B,L,D)
    float* __restrict__ Bm,               // (B,L,NS)
    float* __restrict__ Cm)               // (B,L,NS)
{
    const int ROWS = 16;
    const int WP = 260;
    __shared__ float sW[24 * WP];
    __shared__ float sflow[ROWS * DD];
    __shared__ float sdbl[ROWS * 48];
    int tid = threadIdx.x;
    int row0 = blockIdx.x * ROWS;         // row = b*L + l

    for (int j = 0; j < 4; ++j) {
        int s = tid + j * 256;
        int r = s >> 6, c4 = s & 63;
        int row = row0 + r;
        int b = row >> 9, l = row & 511;
        float4 v = *reinterpret_cast<const float4*>(&flow[(l * BB + b) * DD + c4 * 4]);
        *reinterpret_cast<float4*>(&sflow[r * DD + c4 * 4]) = v;
    }

    for (int half = 0; half < 2; ++half) {
        __syncthreads();
        for (int idx = tid; idx < 24 * DD; idx += 256) {
            int c = idx >> 8, k = idx & 255;
            sW[c * WP + k] = x_proj_w[(half * 24 + c) * DD + k];
        }
        __syncthreads();
        for (int o = tid; o < ROWS * 24; o += 256) {
            int r = o / 24, c = o % 24;
            const float* wrow = &sW[c * WP];
            const float* frow = &sflow[r * DD];
            float s = 0.f;
            for (int k = 0; k < DD; k += 4) {
                float4 fv = *reinterpret_cast<const float4*>(&frow[k]);
                float4 wv = *reinterpret_cast<const float4*>(&wrow[k]);
                s += fv.x * wv.x + fv.y * wv.y + fv.z * wv.z + fv.w * wv.w;
            }
            sdbl[r * 48 + half * 24 + c] = s;
        }
    }
    __syncthreads();

    {
        int r = tid >> 4, c = tid & 15;
        int row = row0 + r;
        Bm[row * NS + c] = sdbl[r * 48 + RK + c];
        Cm[row * NS + c] = sdbl[r * 48 + RK + NS + c];
    }

    float wreg[RK];
    #pragma unroll
    for (int k = 0; k < RK; k += 4) {
        float4 v = *reinterpret_cast<const float4*>(&dt_w[tid * RK + k]);
        wreg[k] = v.x; wreg[k + 1] = v.y; wreg[k + 2] = v.z; wreg[k + 3] = v.w;
    }
    float bias = dt_b[tid];
    for (int r = 0; r < ROWS; ++r) {
        float s = bias;
        #pragma unroll
        for (int k = 0; k < RK; ++k) s = fmaf(sdbl[r * 48 + k], wreg[k], s);
        float sp = fmaxf(s, 0.f) + log1pf(__expf(-fabsf(s)));
        delta[(row0 + r) * DD + tid] = sp;
    }
}

// ---------------- K2 pass A: per-chunk local scan ----------------
// thread (b,d,c): h[16] from 0, aprod[16]; 32 steps
__global__ __launch_bounds__(256) void k2_scanA(
    const float* __restrict__ u_pos,    // (L,B,D)
    const float* __restrict__ A_log,    // (D,NS)
    const float* __restrict__ delta,    // (B,L,D)
    const float* __restrict__ Bm,       // (B,L,NS)
    float* __restrict__ aprod,          // (B,CH,D,NS)
    float* __restrict__ hpart)          // (B,CH,D,NS)
{
    int b = blockIdx.x >> 4;
    int c = blockIdx.x & 15;
    int d = threadIdx.x;
    int l0 = c * LC;

    float a[NS];
    #pragma unroll
    for (int n = 0; n < NS; n += 4) {
        float4 v = *reinterpret_cast<const float4*>(&A_log[d * NS + n]);
        a[n]     = -__expf(v.x) * 1.44269504f;   // fold log2(e): dA = exp2(dlt*a)
        a[n + 1] = -__expf(v.y) * 1.44269504f;
        a[n + 2] = -__expf(v.z) * 1.44269504f;
        a[n + 3] = -__expf(v.w) * 1.44269504f;
    }
    float h[NS], ap[NS];
    #pragma unroll
    for (int n = 0; n < NS; ++n) { h[n] = 0.f; ap[n] = 1.f; }

    const float* dp = delta + ((size_t)b * LL + l0) * DD + d;
    const float* up = u_pos + ((size_t)l0 * BB + b) * DD + d;
    const float* Bp = Bm + ((size_t)b * LL + l0) * NS;

    #pragma unroll 2
    for (int l = 0; l < LC; ++l) {
        float dlt = dp[l * DD];
        float uv  = up[l * BB * DD];
        float Bv[NS];
        LD16(Bv, Bp, l * NS);
        float du = dlt * uv;
        #pragma unroll
        for (int n = 0; n < NS; ++n) {
            float dA = exp2f(dlt * a[n]);
            ap[n] *= dA;
            h[n] = fmaf(dA, h[n], du * Bv[n]);
        }
    }

    size_t o = (((size_t)b * CH + c) * DD + d) * NS;
    #pragma unroll
    for (int n = 0; n < NS; n += 4) {
        *reinterpret_cast<float4*>(&aprod[o + n]) = make_float4(ap[n], ap[n+1], ap[n+2], ap[n+3]);
        *reinterpret_cast<float4*>(&hpart[o + n]) = make_float4(h[n], h[n+1], h[n+2], h[n+3]);
    }
}

// ---------------- K2 pass B: combine chunks ----------------
// thread (b,d,n): sequential over 16 chunks; writes h_in into hpart in-place
__global__ __launch_bounds__(256) void k2_scanB(
    const float* __restrict__ h0,       // (B,D,NS)
    const float* __restrict__ aprod,
    float* __restrict__ hpart,          // in: local scan results; out: h_in per chunk
    float* __restrict__ h_out)          // (B,D,NS)
{
    int t = blockIdx.x * 256 + threadIdx.x;
    int n = t & 15, d = (t >> 4) & 255, b = t >> 12;
    float s = h0[t];
    for (int c = 0; c < CH; ++c) {
        size_t idx = (((size_t)b * CH + c) * DD + d) * NS + n;
        float apv = aprod[idx];
        float hpv = hpart[idx];
        hpart[idx] = s;                 // incoming state for chunk c
        s = fmaf(apv, s, hpv);
    }
    h_out[t] = s;
}

// ---------------- K2 pass C: re-scan with true h_in, emit y ----------------
// y overwrites delta in place (same element read then written by same thread)
__global__ __launch_bounds__(256) void k2_scanC(
    const float* __restrict__ u_pos,
    const float* __restrict__ A_log,
    const float* __restrict__ Dp,
    const float* __restrict__ Bm,
    const float* __restrict__ Cm,
    const float* __restrict__ hpart,    // h_in per chunk
    float* __restrict__ deltaY)         // read delta, write y
{
    int b = blockIdx.x >> 4;
    int c = blockIdx.x & 15;
    int d = threadIdx.x;
    int l0 = c * LC;

    float a[NS];
    #pragma unroll
    for (int n = 0; n < NS; n += 4) {
        float4 v = *reinterpret_cast<const float4*>(&A_log[d * NS + n]);
        a[n]     = -__expf(v.x) * 1.44269504f;
        a[n + 1] = -__expf(v.y) * 1.44269504f;
        a[n + 2] = -__expf(v.z) * 1.44269504f;
        a[n + 3] = -__expf(v.w) * 1.44269504f;
    }
    float h[NS];
    {
        size_t o = (((size_t)b * CH + c) * DD + d) * NS;
        LD16(h, hpart, o);
    }
    float Dd = Dp[d];

    float* dp = deltaY + ((size_t)b * LL + l0) * DD + d;
    const float* up = u_pos + ((size_t)l0 * BB + b) * DD + d;
    const float* Bp = Bm + ((size_t)b * LL + l0) * NS;
    const float* Cp = Cm + ((size_t)b * LL + l0) * NS;

    // prefetched current values
    float dlt = dp[0];
    float uv  = up[0];
    float Bv[NS], Cv[NS];
    LD16(Bv, Bp, 0);
    LD16(Cv, Cp, 0);

    for (int l = 0; l < LC; ++l) {
        int ln = (l + 1 < LC) ? l + 1 : l;        // clamped prefetch
        float dlt_n = dp[ln * DD];
        float uv_n  = up[ln * BB * DD];
        float Bn[NS], Cn[NS];
        LD16(Bn, Bp, ln * NS);
        LD16(Cn, Cp, ln * NS);

        float du = dlt * uv;
        float acc = 0.f;
        #pragma unroll
        for (int n = 0; n < NS; ++n) {
            float dA = exp2f(dlt * a[n]);
            h[n] = fmaf(dA, h[n], du * Bv[n]);
            acc = fmaf(h[n], Cv[n], acc);
        }
        dp[l * DD] = fmaf(uv, Dd, acc);           // y in place of delta

        dlt = dlt_n; uv = uv_n;
        #pragma unroll
        for (int n = 0; n < NS; ++n) { Bv[n] = Bn[n]; Cv[n] = Cn[n]; }
    }
}

// ---------------- K3: output projection ----------------
__global__ __launch_bounds__(256) void k3_out(
    const float* __restrict__ Y,
    const float* __restrict__ W,        // (m,k) row-major
    float* __restrict__ Out)
{
    __shared__ float As[64 * 68];
    __shared__ float Bs[64 * 68];
    int tid = threadIdx.x;
    int row0 = (blockIdx.x >> 2) * 64;
    int col0 = (blockIdx.x & 3) * 64;
    int tx = tid & 15, ty = tid >> 4;
    int r0 = ty * 4, m0 = tx * 4;
    float acc[4][4] = {};

    for (int kc = 0; kc < 256; kc += 64) {
        __syncthreads();
        for (int j = 0; j < 4; ++j) {
            int s = tid + j * 256;
            int r = s >> 4, c4 = s & 15;
            float4 v = *reinterpret_cast<const float4*>(&Y[(row0 + r) * 256 + kc + c4 * 4]);
            As[(c4 * 4 + 0) * 68 + r] = v.x;
            As[(c4 * 4 + 1) * 68 + r] = v.y;
            As[(c4 * 4 + 2) * 68 + r] = v.z;
            As[(c4 * 4 + 3) * 68 + r] = v.w;
        }
        for (int j = 0; j < 4; ++j) {
            int s = tid + j * 256;
            int m = s >> 4, c4 = s & 15;
            float4 v = *reinterpret_cast<const float4*>(&W[(col0 + m) * 256 + kc + c4 * 4]);
            Bs[(c4 * 4 + 0) * 68 + m] = v.x;
            Bs[(c4 * 4 + 1) * 68 + m] = v.y;
            Bs[(c4 * 4 + 2) * 68 + m] = v.z;
            Bs[(c4 * 4 + 3) * 68 + m] = v.w;
        }
        __syncthreads();
        #pragma unroll
        for (int kk = 0; kk < 64; ++kk) {
            float4 av = *reinterpret_cast<const float4*>(&As[kk * 68 + r0]);
            float4 bv = *reinterpret_cast<const float4*>(&Bs[kk * 68 + m0]);
            float aa[4] = {av.x, av.y, av.z, av.w};
            float bb[4] = {bv.x, bv.y, bv.z, bv.w};
            #pragma unroll
            for (int i = 0; i < 4; ++i)
                #pragma unroll
                for (int jj = 0; jj < 4; ++jj)
                    acc[i][jj] = fmaf(aa[i], bb[jj], acc[i][jj]);
        }
    }
    for (int i = 0; i < 4; ++i) {
        float4 v = make_float4(acc[i][0], acc[i][1], acc[i][2], acc[i][3]);
        *reinterpret_cast<float4*>(&Out[(row0 + r0 + i) * 256 + col0 + m0]) = v;
    }
}

extern "C" void kernel_launch(void* const* d_in, const int* in_sizes, int n_in,
                              void* d_out, int out_size, void* d_ws, size_t ws_size,
                              hipStream_t stream) {
    const float* pos  = (const float*)d_in[0];   // (L,B,D)
    const float* flow = (const float*)d_in[1];   // (L,B,D)
    const float* h0   = (const float*)d_in[2];   // (B,D,NS)
    const float* xw   = (const float*)d_in[3];   // (48,D)
    const float* dtw  = (const float*)d_in[4];   // (D,16)
    const float* dtb  = (const float*)d_in[5];   // (D)
    const float* alog = (const float*)d_in[6];   // (D,NS)
    const float* dpar = (const float*)d_in[7];   // (D)
    const float* ow   = (const float*)d_in[8];   // (D_MODEL, D_INNER)

    float* out = (float*)d_out;                  // out0: 4,194,304 then h_final: 131,072

    float* ws    = (float*)d_ws;
    float* delta = ws;                 // 4,194,304 floats (y overwrites in pass C)
    float* Bmw   = ws + 4194304;       //   262,144
    float* Cmw   = ws + 4456448;       //   262,144
    float* aprod = ws + 4718592;       // 2,097,152
    float* hpart = ws + 6815744;       // 2,097,152  (total 35.7 MB)

    float* h_out = out + 32 * 512 * 256;

    k1_proj<<<1024, 256, 0, stream>>>(flow, xw, dtw, dtb, delta, Bmw, Cmw);
    k2_scanA<<<512, 256, 0, stream>>>(pos, alog, delta, Bmw, aprod, hpart);
    k2_scanB<<<512, 256, 0, stream>>>(h0, aprod, hpart, h_out);
    k2_scanC<<<512, 256, 0, stream>>>(pos, alog, dpar, Bmw, Cmw, hpart, delta);
    k3_out<<<1024, 256, 0, stream>>>(delta, ow, out);
}